// Round 8
// baseline (3483.778 us; speedup 1.0000x reference)
//
#include <hip/hip_runtime.h>

typedef unsigned int u32;
typedef unsigned short u16;
typedef unsigned long long u64;

typedef __attribute__((ext_vector_type(8))) short bf16x8;
typedef __attribute__((ext_vector_type(4))) float f32x4;

__device__ __forceinline__ u16 f2bf(float f) {
    u32 u = __float_as_uint(f);
    u += 0x7fffu + ((u >> 16) & 1u);
    return (u16)(u >> 16);
}
__device__ __forceinline__ float bf2f(u16 h) {
    return __uint_as_float(((u32)h) << 16);
}

// ---------------------------------------------------------------------------
// prep: convert/transpose weights to bf16; build U2F (fragment-major U2 for
// gru2's streaming MFMA: U2F[nt][ks][lane][8], 40 tiles x 7 ksteps x 1KB,
// zero-padded for row>=600 / k>=200); zero hbuf1 ring + claim counters.
// ---------------------------------------------------------------------------
__global__ __launch_bounds__(256) void prep_kernel(
    const float* __restrict__ W1, const float* __restrict__ W2,
    const float* __restrict__ U1, const float* __restrict__ U2,
    u16* __restrict__ W1T, u16* __restrict__ W2T,
    u16* __restrict__ U1T, u16* __restrict__ U2F,
    u32* __restrict__ hzero)
{
    int i = blockIdx.x * 256 + threadIdx.x;
    if (i < 240000) { int j = i / 200, k = i - j * 200; W1T[i] = f2bf(W1[k * 1200 + j]); return; }
    i -= 240000;
    if (i < 240000) { int j = i / 400, k = i - j * 400; W2T[i] = f2bf(W2[k * 600 + j]); return; }
    i -= 240000;
    if (i < 480000) { int j = i / 400, k = i - j * 400; U1T[i] = f2bf(U1[k * 1200 + j]); return; }
    i -= 480000;
    if (i < 143360) {
        // U2F: i = ((nt*7 + ks)*64 + lane)*8 + j
        int nt = i / 3584, r = i - nt * 3584;
        int ks = r / 512, q = r - ks * 512;
        int lane = q >> 3, j = q & 7;
        int col = nt * 16 + (lane & 15);
        int k = ks * 32 + ((lane >> 4) << 3) + j;
        U2F[i] = (col < 600 && k < 200) ? f2bf(U2[k * 600 + col]) : (u16)0;
        return;
    }
    i -= 143360;
    if (i < 204816) {
        if (i < 204800) hzero[i] = 0u;                 // hbuf1 ring
        else hzero[307200 + (i - 204800)] = 0u;        // clm1 + clm2 (16 u32)
    }
}

// ---------------------------------------------------------------------------
// embed + batchnorm -> x bf16, layout [t*128 + b][200]
// ---------------------------------------------------------------------------
__global__ __launch_bounds__(256) void embed_bn_kernel(
    const int* __restrict__ tokens, const float* __restrict__ emb,
    const float* __restrict__ gamma, const float* __restrict__ beta,
    const float* __restrict__ mmean, const float* __restrict__ mvar,
    u16* __restrict__ x)
{
    int gid = blockIdx.x * 256 + threadIdx.x;  // 6,553,600 total
    int r = gid / 200, e = gid - r * 200;
    int t = r >> 7, b = r & 127;               // r = t*128 + b
    int tok = tokens[b * 256 + t];
    float v = (emb[(size_t)tok * 200 + e] - mmean[e]) *
              (1.0f / sqrtf(mvar[e] + 1e-3f)) * gamma[e] + beta[e];
    x[gid] = f2bf(v);
}

// ---------------------------------------------------------------------------
// GEMM: C[M][N] (bf16) = A[M][KEL] (bf16) @ B[KEL][N] + bias, B given as
// BT[N][KEL]. Tile 64x64 per 256-thread WG; MFMA 16x16x32 bf16.
// ---------------------------------------------------------------------------
template<int KEL, int KSTEPS, int KPAD>
__global__ __launch_bounds__(256) void gemm_bias_kernel(
    const u16* __restrict__ A, const u16* __restrict__ BT,
    const float* __restrict__ bias, u16* __restrict__ C, int N)
{
    __shared__ u16 A_lds[64 * KPAD];
    __shared__ u16 B_lds[64 * KPAD];
    const int m0 = blockIdx.x * 64, n0 = blockIdx.y * 64;
    const int tid = threadIdx.x;
    const int lane = tid & 63, wave = tid >> 6;
    const int l15 = lane & 15, lq = lane >> 4;

    for (int idx = tid; idx < 64 * (KPAD / 2); idx += 256) {
        int row = idx / (KPAD / 2), kp = idx % (KPAD / 2);
        int k = kp * 2;
        u32 va = (k < KEL) ? *(const u32*)(A + (size_t)(m0 + row) * KEL + k) : 0u;
        *(u32*)(A_lds + row * KPAD + k) = va;
        int gn = n0 + row;
        u32 vb = (k < KEL && gn < N) ? *(const u32*)(BT + (size_t)gn * KEL + k) : 0u;
        *(u32*)(B_lds + row * KPAD + k) = vb;
    }
    __syncthreads();

    f32x4 acc[4];
    for (int i = 0; i < 4; ++i) acc[i] = (f32x4){0.f, 0.f, 0.f, 0.f};
    for (int ks = 0; ks < KSTEPS; ++ks) {
        bf16x8 a = *(const bf16x8*)(A_lds + (wave * 16 + l15) * KPAD + ks * 32 + lq * 8);
        for (int nt = 0; nt < 4; ++nt) {
            bf16x8 b = *(const bf16x8*)(B_lds + (nt * 16 + l15) * KPAD + ks * 32 + lq * 8);
            acc[nt] = __builtin_amdgcn_mfma_f32_16x16x32_bf16(a, b, acc[nt], 0, 0, 0);
        }
    }
    for (int nt = 0; nt < 4; ++nt) {
        int col = n0 + nt * 16 + l15;
        if (col < N) {
            float bv = bias[col];
            for (int i = 0; i < 4; ++i) {
                int row = m0 + wave * 16 + lq * 4 + i;
                C[(size_t)row * N + col] = f2bf(acc[nt][i] + bv);
            }
        }
    }
}

// ---------------------------------------------------------------------------
// Persistent GRU scan (GRU1), SELF-TAGGED h exchange, DEPTH-4 ring,
// agent-scope ops (round-4/7 proven). XCD-affinity claiming keeps a group's
// WGs on one XCD (3x HBM-fetch cut). Tokens staged to LDS once; tags
// published before output stores.
// ---------------------------------------------------------------------------
template<int UH, int G, int KSTEPS, int KPAD, int HS, int NC, int NCP, int NT,
         int MAXT, int MAXE, int NH, bool WB16>
__global__ __launch_bounds__(256) void gru_kernel(
    const u16* __restrict__ xw,      // [256*128][3*UH] bf16 (row = t*128+b)
    const u16* __restrict__ UT,      // [3*UH][UH] bf16 (transposed U)
    const float* __restrict__ br,    // [3*UH] recurrent bias
    const int* __restrict__ tokens,  // [128][256]
    float* __restrict__ out_f32,     // [128][256][UH]
    u16* __restrict__ out_b16,       // [256*128][UH] or unused
    float* __restrict__ h_final,     // [128][UH]
    u32* __restrict__ hbuf,          // [8][4][16][UH] tagged u32
    u32* __restrict__ claims)        // [8] claim counters (zeroed by prep)
{
    __shared__ u16 U_lds[NCP * KPAD];
    __shared__ u16 h_lds[16 * KPAD];
    __shared__ float rec_lds[16 * NCP];
    __shared__ unsigned char tok_lds[16 * 256];
    __shared__ int claim_s[2];

    const int tid = threadIdx.x;

    if (tid == 0) {
        u32 xcc;
        asm volatile("s_getreg_b32 %0, hwreg(HW_REG_XCC_ID)" : "=s"(xcc));
        int x = (int)(xcc & 7u);
        int cg = -1, cw = -1;
        for (int a = 0; a < 8; ++a) {
            int gg = (x + a) & 7;
            u32 ww = atomicAdd(&claims[gg], 1u);
            if (ww < (u32)G) { cg = gg; cw = (int)ww; break; }
        }
        claim_s[0] = cg; claim_s[1] = cw;
    }
    __syncthreads();
    const int g = claim_s[0], w = claim_s[1];

    const int b0 = g * 16;
    const int lane = tid & 63, wave = tid >> 6;
    const int l15 = lane & 15, lq = lane >> 4;

    for (int i = tid; i < NCP * KPAD / 2; i += 256) ((u32*)U_lds)[i] = 0u;
    for (int i = tid; i < 16 * KPAD / 2; i += 256) ((u32*)h_lds)[i] = 0u;
    __syncthreads();
    for (int idx = tid; idx < NC * (UH / 2); idx += 256) {
        int c = idx / (UH / 2), kp = idx % (UH / 2);
        int j = (c / HS) * UH + w * HS + (c % HS);
        u32 v = *(const u32*)(UT + (size_t)j * UH + kp * 2);
        *(u32*)(U_lds + c * KPAD + kp * 2) = v;
    }
    for (int i = tid; i < 16 * 256; i += 256) {
        int b = i >> 8, tt = i & 255;
        tok_lds[i] = (tokens[(b0 + b) * 256 + tt] != 0) ? 1 : 0;
    }

    int ne = 0;
    int eb[MAXE], eco[MAXE], eih[MAXE], egb[MAXE], exwoff[MAXE];
    float ebrz[MAXE], ebrr[MAXE], ebrh[MAXE], hold[MAXE];
    for (int u = tid; u < 16 * HS; u += 256) {
        int b = u / HS, co = u % HS;
        int ih = w * HS + co;
        eb[ne] = b; eco[ne] = co; eih[ne] = ih; egb[ne] = b0 + b;
        exwoff[ne] = (b0 + b) * 3 * UH;
        ebrz[ne] = br[ih]; ebrr[ne] = br[UH + ih]; ebrh[ne] = br[2 * UH + ih];
        hold[ne] = 0.f;
        ++ne;
    }

    constexpr int TOT = 16 * UH / 2;   // u64 slots total
    u32 pend0 = 0;
    int soff[NH], loff[NH];
    for (int i = 0; i < NH; ++i) {
        int s = tid + i * 256;
        if (s < TOT) {
            int b = s / (UH / 2), kk = s % (UH / 2);
            soff[i] = b * UH + kk * 2;
            loff[i] = b * KPAD + kk * 2;
            pend0 |= 1u << i;
        } else { soff[i] = 0; loff[i] = 0; }
    }

    u32* hb = hbuf + (size_t)g * 4 * 16 * UH;

    for (int t = 0; t < 256; ++t) {
        float xzv[MAXE], xrv[MAXE], xhv[MAXE];
        for (int e = 0; e < ne; ++e) {
            const u16* xrow = xw + (size_t)t * (128 * 3 * UH) + exwoff[e];
            xzv[e] = bf2f(xrow[eih[e]]);
            xrv[e] = bf2f(xrow[UH + eih[e]]);
            xhv[e] = bf2f(xrow[2 * UH + eih[e]]);
        }

        const u32* hsrc = hb + (t & 3) * 16 * UH;
        const u32 want = (u32)t & 0xFFFFu;
        u32 pend = pend0;
        while (pend) {
            u64 tmp[NH];
            #pragma unroll
            for (int i = 0; i < NH; ++i)
                if (pend & (1u << i))
                    tmp[i] = __hip_atomic_load((const u64*)(hsrc + soff[i]),
                                               __ATOMIC_RELAXED,
                                               __HIP_MEMORY_SCOPE_AGENT);
            #pragma unroll
            for (int i = 0; i < NH; ++i)
                if (pend & (1u << i)) {
                    u64 v = tmp[i];
                    if ((u32)(v & 0xFFFFu) == want &&
                        ((u32)(v >> 32) & 0xFFFFu) == want) {
                        u32 pk = ((u32)(v >> 16) & 0xFFFFu) | ((u32)(v >> 48) << 16);
                        *(u32*)(h_lds + loff[i]) = pk;
                        pend &= ~(1u << i);
                    }
                }
            if (pend) __builtin_amdgcn_s_sleep(1);
        }
        __syncthreads();

        f32x4 acc[MAXT];
        for (int ti = 0; ti < MAXT; ++ti) acc[ti] = (f32x4){0.f, 0.f, 0.f, 0.f};
        for (int ks = 0; ks < KSTEPS; ++ks) {
            bf16x8 a = *(const bf16x8*)(h_lds + l15 * KPAD + ks * 32 + lq * 8);
            int ti = 0;
            for (int nt = wave; nt < NT; nt += 4, ++ti) {
                bf16x8 b = *(const bf16x8*)(U_lds + (nt * 16 + l15) * KPAD + ks * 32 + lq * 8);
                acc[ti] = __builtin_amdgcn_mfma_f32_16x16x32_bf16(a, b, acc[ti], 0, 0, 0);
            }
        }
        {
            int ti = 0;
            for (int nt = wave; nt < NT; nt += 4, ++ti)
                for (int i = 0; i < 4; ++i)
                    rec_lds[(lq * 4 + i) * NCP + nt * 16 + l15] = acc[ti][i];
        }
        __syncthreads();

        u32* hdst = hb + ((t + 1) & 3) * 16 * UH;
        float hnv[MAXE];
        u32 tgv[MAXE];
        for (int e = 0; e < ne; ++e) {
            int b = eb[e], co = eco[e];
            float rz = rec_lds[b * NCP + co] + ebrz[e];
            float rr = rec_lds[b * NCP + HS + co] + ebrr[e];
            float rh = rec_lds[b * NCP + 2 * HS + co] + ebrh[e];
            float z = 1.f / (1.f + __expf(-(xzv[e] + rz)));
            float r = 1.f / (1.f + __expf(-(xrv[e] + rr)));
            float pre = xhv[e] + r * rh;
            float th = 2.f / (1.f + __expf(-2.f * pre)) - 1.f;
            float hn = z * hold[e] + (1.f - z) * th;
            if (!tok_lds[b * 256 + t]) hn = hold[e];   // masked: carry state
            hold[e] = hn;
            hnv[e] = hn;
            tgv[e] = ((u32)f2bf(hn) << 16) | (u32)(t + 1);
        }
        for (int e = 0; e < ne; ++e)
            __hip_atomic_store(hdst + eb[e] * UH + eih[e], tgv[e],
                               __ATOMIC_RELAXED, __HIP_MEMORY_SCOPE_AGENT);
        for (int e = 0; e < ne; ++e) {
            int gb = egb[e], ih = eih[e];
            out_f32[((size_t)gb * 256 + t) * UH + ih] = hnv[e];
            if (WB16) out_b16[(size_t)(t * 128 + gb) * UH + ih] = (u16)(tgv[e] >> 16);
            if (t == 255) h_final[(size_t)gb * UH + ih] = hnv[e];
        }
    }
}

// ---------------------------------------------------------------------------
// GRU2, exchange-free, L2-STREAMING U2. One 512-thread WG per 16-batch
// group (8 WGs). B-fragments are h-independent and step-invariant, so each
// step re-loads them from U2F (fragment-major, 1KB contiguous per
// (tile,kstep) per wave -> perfectly coalesced dwordx4; L2-resident after
// step 0: 287 KB << 4 MiB/XCD). No persistent register array -> nothing for
// the allocator to spill (the round-0/1/7 failure mode). Bias via per-elem
// br adds in the gate phase (no ones-row).
// ---------------------------------------------------------------------------
__global__ __launch_bounds__(512, 1) void gru2_kernel(
    const u16* __restrict__ xw,      // [256*128][600] bf16 (row = t*128+b)
    const u16* __restrict__ U2F,     // [40][7][64][8] bf16 fragments
    const float* __restrict__ br,    // [600] recurrent bias
    const int* __restrict__ tokens,  // [128][256]
    float* __restrict__ out_f32,     // [128][256][200]
    float* __restrict__ h_final)     // [128][200]
{
    __shared__ u16 h_lds[16 * 232];          // [batch][k], k>=200 stays 0
    __shared__ float rec_lds[16 * 616];      // [batch][gatecol 0..607]
    __shared__ unsigned char mask_lds[16 * 256];

    const int g = blockIdx.x;                // 8 groups of 16 batches
    const int b0 = g * 16;
    const int tid = threadIdx.x;             // 0..511 (8 waves)
    const int lane = tid & 63, wave = tid >> 6;
    const int l15 = lane & 15, lq = lane >> 4;

    for (int i = tid; i < 16 * 232 / 2; i += 512) ((u32*)h_lds)[i] = 0u;
    for (int i = tid; i < 16 * 256; i += 512) {
        int b = i >> 8, t = i & 255;
        mask_lds[i] = (tokens[(b0 + b) * 256 + t] != 0) ? 1 : 0;
    }

    // per-thread gate elements: u = tid + e*512, u < 16*200
    int be[7], ce[7];
    float ebrz[7], ebrr[7], ebrh[7], hold[7];
    #pragma unroll
    for (int e = 0; e < 7; ++e) {
        int u = tid + e * 512;
        int b = u / 200, co = u - b * 200;
        be[e] = b; ce[e] = co; hold[e] = 0.f;
        if (u < 3200) {
            ebrz[e] = br[co]; ebrr[e] = br[200 + co]; ebrh[e] = br[400 + co];
        } else { ebrz[e] = ebrr[e] = ebrh[e] = 0.f; }
    }
    __syncthreads();

    for (int t = 0; t < 256; ++t) {
        // phase 1: prefetch gate inputs (latency hides under MFMA phase)
        float xzv[7], xrv[7], xhv[7];
        const u16* xbase = xw + (size_t)t * (128 * 600);
        #pragma unroll
        for (int e = 0; e < 7; ++e) {
            if (tid + e * 512 < 3200) {
                const u16* xr = xbase + (size_t)(b0 + be[e]) * 600 + ce[e];
                xzv[e] = bf2f(xr[0]);
                xrv[e] = bf2f(xr[200]);
                xhv[e] = bf2f(xr[400]);
            }
        }

        // phase 2: rec = h @ U, B-fragments streamed from L2 every step
        f32x4 acc[5];
        #pragma unroll
        for (int it = 0; it < 5; ++it) acc[it] = (f32x4){0.f, 0.f, 0.f, 0.f};
        #pragma unroll
        for (int ks = 0; ks < 7; ++ks) {
            bf16x8 a = *(const bf16x8*)(h_lds + l15 * 232 + ks * 32 + lq * 8);
            #pragma unroll
            for (int it = 0; it < 5; ++it) {
                int nt = wave * 5 + it;
                bf16x8 bfrag = *(const bf16x8*)(
                    U2F + ((size_t)(nt * 7 + ks) * 64 + lane) * 8);
                acc[it] = __builtin_amdgcn_mfma_f32_16x16x32_bf16(
                    a, bfrag, acc[it], 0, 0, 0);
            }
        }
        #pragma unroll
        for (int it = 0; it < 5; ++it) {
            int nt = wave * 5 + it;
            if (nt < 38) {
                #pragma unroll
                for (int i = 0; i < 4; ++i)
                    rec_lds[(lq * 4 + i) * 616 + nt * 16 + l15] = acc[it][i];
            }
        }
        __syncthreads();

        // phase 3: gates + state update
        #pragma unroll
        for (int e = 0; e < 7; ++e) {
            if (tid + e * 512 < 3200) {
                int b = be[e], co = ce[e];
                float rz = rec_lds[b * 616 + co] + ebrz[e];
                float rr = rec_lds[b * 616 + 200 + co] + ebrr[e];
                float rh = rec_lds[b * 616 + 400 + co] + ebrh[e];
                float z = 1.f / (1.f + __expf(-(xzv[e] + rz)));
                float r = 1.f / (1.f + __expf(-(xrv[e] + rr)));
                float pre = xhv[e] + r * rh;
                float th = 2.f / (1.f + __expf(-2.f * pre)) - 1.f;
                float hn = z * hold[e] + (1.f - z) * th;
                if (!mask_lds[b * 256 + t]) hn = hold[e];   // masked: carry
                hold[e] = hn;
                h_lds[b * 232 + co] = f2bf(hn);
                out_f32[((size_t)(b0 + b) * 256 + t) * 200 + co] = hn;
                if (t == 255) h_final[(size_t)(b0 + b) * 200 + co] = hn;
            }
        }
        __syncthreads();
    }
}

// ---------------------------------------------------------------------------
// launch
// ---------------------------------------------------------------------------
extern "C" void kernel_launch(void* const* d_in, const int* in_sizes, int n_in,
                              void* d_out, int out_size, void* d_ws, size_t ws_size,
                              hipStream_t stream)
{
    const int*   tokens = (const int*)d_in[0];
    const float* emb    = (const float*)d_in[1];
    const float* gamma  = (const float*)d_in[2];
    const float* beta   = (const float*)d_in[3];
    const float* mmean  = (const float*)d_in[4];
    const float* mvar   = (const float*)d_in[5];
    const float* W1     = (const float*)d_in[6];
    const float* U1     = (const float*)d_in[7];
    const float* b1     = (const float*)d_in[8];
    const float* W2     = (const float*)d_in[9];
    const float* U2     = (const float*)d_in[10];
    const float* b2     = (const float*)d_in[11];

    float* out = (float*)d_out;
    char* ws = (char*)d_ws;

    u16* x     = (u16*)(ws + 0);            // 32768*200*2  = 13,107,200
    u16* xw1   = (u16*)(ws + 13107200);     // 32768*1200*2 = 78,643,200
    u16* o1b   = (u16*)(ws + 91750400);     // 32768*400*2  = 26,214,400
    u16* xw2   = (u16*)(ws + 117964800);    // 32768*600*2  = 39,321,600
    u16* W1T   = (u16*)(ws + 157286400);    // 480,000
    u16* W2T   = (u16*)(ws + 157766400);    // 480,000
    u16* U1T   = (u16*)(ws + 158246400);    // 960,000
    // (old U2T slot at 159206400 unused)
    u32* hbuf1 = (u32*)(ws + 159446400);    // 8*4*16*400 u32 = 819,200 B
    u16* U2F   = (u16*)(ws + 160265600);    // 40*7*512 u16 = 286,720 B
    u32* clm1  = (u32*)(ws + 160675200);    // 8 u32 (word 307200 from hbuf1)
    // clm2 at 160675232 (zeroed, unused)

    float* out2 = out;              // [128,256,200]
    float* out1 = out + 6553600;    // [128,256,400]
    float* h2   = out + 19660800;   // [128,200]
    float* h1   = out + 19686400;   // [128,400]

    // total prep work items: 240000+240000+480000+143360+204816 = 1,308,176
    prep_kernel<<<5111, 256, 0, stream>>>(W1, W2, U1, U2, W1T, W2T, U1T, U2F,
                                          hbuf1);
    embed_bn_kernel<<<25600, 256, 0, stream>>>(tokens, emb, gamma, beta, mmean,
                                               mvar, x);
    // xw1 = x @ W1 + bi1   ([32768,200]@[200,1200])
    gemm_bias_kernel<200, 7, 232><<<dim3(512, 19), 256, 0, stream>>>(
        x, W1T, b1, xw1, 1200);
    // GRU1: UH=400, G=16 (128 WGs), HS=25, NT=5, NH=13 (3200 u64 slots)
    gru_kernel<400, 16, 13, 424, 25, 75, 80, 5, 2, 2, 13, true><<<128, 256, 0, stream>>>(
        xw1, U1T, b1 + 1200, tokens, out1, o1b, h1, hbuf1, clm1);
    // xw2 = out1 @ W2 + bi2   ([32768,400]@[400,600])
    gemm_bias_kernel<400, 13, 424><<<dim3(512, 10), 256, 0, stream>>>(
        o1b, W2T, b2, xw2, 600);
    // GRU2: exchange-free, 8 WGs x 512 threads, U2 streamed from L2
    gru2_kernel<<<8, 512, 0, stream>>>(xw2, U2F, b2 + 600, tokens, out2, h2);
}

// Round 9
// 2209.101 us; speedup vs baseline: 1.5770x; 1.5770x over previous
//
#include <hip/hip_runtime.h>

typedef unsigned int u32;
typedef unsigned short u16;
typedef unsigned long long u64;

typedef __attribute__((ext_vector_type(8))) short bf16x8;
typedef __attribute__((ext_vector_type(4))) float f32x4;

__device__ __forceinline__ u16 f2bf(float f) {
    u32 u = __float_as_uint(f);
    u += 0x7fffu + ((u >> 16) & 1u);
    return (u16)(u >> 16);
}
__device__ __forceinline__ float bf2f(u16 h) {
    return __uint_as_float(((u32)h) << 16);
}

// ---------------------------------------------------------------------------
// prep: convert/transpose weights to bf16 (W1T,W2T,U1T,U2T), zero both
// tagged h-exchange rings (depth-4) + control block (clmA[8],clmB[8],sent[8]).
// Zero extent: 204800 + 102400 + 24 (+8 pad) = 307,232 u32 from hbuf1 base.
// ---------------------------------------------------------------------------
__global__ __launch_bounds__(256) void prep_kernel(
    const float* __restrict__ W1, const float* __restrict__ W2,
    const float* __restrict__ U1, const float* __restrict__ U2,
    u16* __restrict__ W1T, u16* __restrict__ W2T,
    u16* __restrict__ U1T, u16* __restrict__ U2T,
    u32* __restrict__ hzero)
{
    int i = blockIdx.x * 256 + threadIdx.x;
    if (i < 240000) { int j = i / 200, k = i - j * 200; W1T[i] = f2bf(W1[k * 1200 + j]); return; }
    i -= 240000;
    if (i < 240000) { int j = i / 400, k = i - j * 400; W2T[i] = f2bf(W2[k * 600 + j]); return; }
    i -= 240000;
    if (i < 480000) { int j = i / 400, k = i - j * 400; U1T[i] = f2bf(U1[k * 1200 + j]); return; }
    i -= 480000;
    if (i < 120000) { int j = i / 200, k = i - j * 200; U2T[i] = f2bf(U2[k * 600 + j]); return; }
    i -= 120000;
    if (i < 307232) hzero[i] = 0u;   // hbuf1 + hbuf2 + ctrl
}

// ---------------------------------------------------------------------------
// embed + batchnorm -> x bf16, layout [t*128 + b][200]
// ---------------------------------------------------------------------------
__global__ __launch_bounds__(256) void embed_bn_kernel(
    const int* __restrict__ tokens, const float* __restrict__ emb,
    const float* __restrict__ gamma, const float* __restrict__ beta,
    const float* __restrict__ mmean, const float* __restrict__ mvar,
    u16* __restrict__ x)
{
    int gid = blockIdx.x * 256 + threadIdx.x;  // 6,553,600 total
    int r = gid / 200, e = gid - r * 200;
    int t = r >> 7, b = r & 127;               // r = t*128 + b
    int tok = tokens[b * 256 + t];
    float v = (emb[(size_t)tok * 200 + e] - mmean[e]) *
              (1.0f / sqrtf(mvar[e] + 1e-3f)) * gamma[e] + beta[e];
    x[gid] = f2bf(v);
}

// ---------------------------------------------------------------------------
// GEMM: C[M][N] (bf16) = A[M][KEL] @ B[KEL][N] + bias (B given as BT[N][KEL]).
// Used only for xw1 = x @ W1 + bi1 now.
// ---------------------------------------------------------------------------
template<int KEL, int KSTEPS, int KPAD>
__global__ __launch_bounds__(256) void gemm_bias_kernel(
    const u16* __restrict__ A, const u16* __restrict__ BT,
    const float* __restrict__ bias, u16* __restrict__ C, int N)
{
    __shared__ u16 A_lds[64 * KPAD];
    __shared__ u16 B_lds[64 * KPAD];
    const int m0 = blockIdx.x * 64, n0 = blockIdx.y * 64;
    const int tid = threadIdx.x;
    const int lane = tid & 63, wave = tid >> 6;
    const int l15 = lane & 15, lq = lane >> 4;

    for (int idx = tid; idx < 64 * (KPAD / 2); idx += 256) {
        int row = idx / (KPAD / 2), kp = idx % (KPAD / 2);
        int k = kp * 2;
        u32 va = (k < KEL) ? *(const u32*)(A + (size_t)(m0 + row) * KEL + k) : 0u;
        *(u32*)(A_lds + row * KPAD + k) = va;
        int gn = n0 + row;
        u32 vb = (k < KEL && gn < N) ? *(const u32*)(BT + (size_t)gn * KEL + k) : 0u;
        *(u32*)(B_lds + row * KPAD + k) = vb;
    }
    __syncthreads();

    f32x4 acc[4];
    for (int i = 0; i < 4; ++i) acc[i] = (f32x4){0.f, 0.f, 0.f, 0.f};
    for (int ks = 0; ks < KSTEPS; ++ks) {
        bf16x8 a = *(const bf16x8*)(A_lds + (wave * 16 + l15) * KPAD + ks * 32 + lq * 8);
        for (int nt = 0; nt < 4; ++nt) {
            bf16x8 b = *(const bf16x8*)(B_lds + (nt * 16 + l15) * KPAD + ks * 32 + lq * 8);
            acc[nt] = __builtin_amdgcn_mfma_f32_16x16x32_bf16(a, b, acc[nt], 0, 0, 0);
        }
    }
    for (int nt = 0; nt < 4; ++nt) {
        int col = n0 + nt * 16 + l15;
        if (col < N) {
            float bv = bias[col];
            for (int i = 0; i < 4; ++i) {
                int row = m0 + wave * 16 + lq * 4 + i;
                C[(size_t)row * N + col] = f2bf(acc[nt][i] + bv);
            }
        }
    }
}

// ---------------------------------------------------------------------------
// FUSED GRU1+GRU2 pipeline kernel, 192 WGs x 256 threads.
//   role 0 (128 WGs): GRU1 — proven tagged-exchange scan (depth-4 ring,
//     agent-scope), XCD-affinity claimed, PLUS a per-step group sentinel:
//     outputs drained (vmcnt0) -> atomicAdd(sent[g]) (monotonic).
//   role 1 (64 WGs, 8/group): GRU2 — per step: poll sent[g] >= 16*(t+1),
//     stage out1[t] tile (bf16) to LDS, compute xw2-part = o1b@W2slice via
//     MFMA (W2 slice LDS-resident, 68KB) and rec-part = h2@U2slice (37KB
//     LDS), own tagged h2 exchange. Replaces gemm2 + old gru2 entirely and
//     overlaps GRU2 behind GRU1 with ~1-step lag.
// Deadlock-free: GRU1 never waits on GRU2; monotonic sentinel is correct
// even if GRU2 WGs are scheduled after GRU1 retires (degrades to serial).
// Producer->consumer visibility: data stores drained to coherence point
// (vmcnt0) BEFORE the sentinel add; consumer loads issued after observing
// the count therefore see the data.
// reset_after note: xw-part and rec-part kept in SEPARATE accumulators
// (r multiplies only the recurrent part of the h-gate).
// ---------------------------------------------------------------------------
__global__ __launch_bounds__(256) void fused_gru_kernel(
    const u16* __restrict__ xw1,     // [256*128][1200] bf16
    const u16* __restrict__ U1T,     // [1200][400] bf16
    const float* __restrict__ br1,   // [1200] recurrent bias GRU1
    const u16* __restrict__ W2T,     // [600][400] bf16
    const u16* __restrict__ U2T,     // [600][200] bf16
    const float* __restrict__ b2,    // [2][600]: bi2 then br2
    const int* __restrict__ tokens,  // [128][256]
    float* __restrict__ out1,        // [128][256][400]
    u16* __restrict__ o1b,           // [256*128][400] bf16 (GRU1 -> GRU2)
    float* __restrict__ h1f,         // [128][400]
    float* __restrict__ out2,        // [128][256][200]
    float* __restrict__ h2f,         // [128][200]
    u32* __restrict__ hbuf1,         // [8][4][16][400] tagged u32
    u32* __restrict__ hbuf2,         // [8][4][16][200] tagged u32
    u32* __restrict__ ctrl)          // [24]: clmA[8], clmB[8], sent[8]
{
    __shared__ __align__(16) char smem[140288];
    __shared__ int claim_s[3];
    const int tid = threadIdx.x;

    // --- role + XCD-affinity claim (GRU1 slots first, then GRU2) ---
    if (tid == 0) {
        u32 xcc;
        asm volatile("s_getreg_b32 %0, hwreg(HW_REG_XCC_ID)" : "=s"(xcc));
        int x = (int)(xcc & 7u);
        int role = -1, cg = -1, cw = -1;
        for (int a = 0; a < 8 && role < 0; ++a) {
            int gg = (x + a) & 7;
            u32 ww = atomicAdd(&ctrl[gg], 1u);
            if (ww < 16u) { role = 0; cg = gg; cw = (int)ww; }
        }
        for (int a = 0; a < 8 && role < 0; ++a) {
            int gg = (x + a) & 7;
            u32 ww = atomicAdd(&ctrl[8 + gg], 1u);
            if (ww < 8u) { role = 1; cg = gg; cw = (int)ww; }
        }
        claim_s[0] = role; claim_s[1] = cg; claim_s[2] = cw;
    }
    __syncthreads();
    const int role = claim_s[0], g = claim_s[1], w = claim_s[2];
    const int b0 = g * 16;
    const int lane = tid & 63, wave = tid >> 6;
    const int l15 = lane & 15, lq = lane >> 4;

    if (role == 0) {
        // ===================== GRU1 =====================
        u16* U_lds = (u16*)smem;                       // 80*424*2 = 67840
        u16* h_lds = (u16*)(smem + 67840);             // 16*424*2 = 13568
        float* rec_lds = (float*)(smem + 81408);       // 16*80*4  = 5120
        unsigned char* tok_lds = (unsigned char*)(smem + 86528);  // 4096

        for (int i = tid; i < 16960; i += 256) ((u32*)U_lds)[i] = 0u;
        for (int i = tid; i < 3392; i += 256) ((u32*)h_lds)[i] = 0u;
        __syncthreads();
        for (int idx = tid; idx < 15000; idx += 256) {      // 75 cols x 200
            int c = idx / 200, kp = idx - (idx / 200) * 200;
            int j = (c / 25) * 400 + w * 25 + (c % 25);
            *(u32*)(U_lds + c * 424 + kp * 2) =
                *(const u32*)(U1T + (size_t)j * 400 + kp * 2);
        }
        for (int i = tid; i < 4096; i += 256) {
            int b = i >> 8, tt = i & 255;
            tok_lds[i] = (tokens[(b0 + b) * 256 + tt] != 0) ? 1 : 0;
        }

        int ne = 0;
        int eb[2], eco[2], eih[2], egb[2], exw[2];
        float ebrz[2], ebrr[2], ebrh[2], hold[2];
        for (int u = tid; u < 400; u += 256) {
            int b = u / 25, co = u % 25;
            int ih = w * 25 + co;
            eb[ne] = b; eco[ne] = co; eih[ne] = ih; egb[ne] = b0 + b;
            exw[ne] = (b0 + b) * 1200;
            ebrz[ne] = br1[ih]; ebrr[ne] = br1[400 + ih]; ebrh[ne] = br1[800 + ih];
            hold[ne] = 0.f; ++ne;
        }
        u32 pend0 = 0; int soff[13], loff[13];
        for (int i = 0; i < 13; ++i) {
            int s = tid + i * 256;
            if (s < 3200) {
                int b = s / 200, kk = s % 200;
                soff[i] = b * 400 + kk * 2; loff[i] = b * 424 + kk * 2;
                pend0 |= 1u << i;
            } else { soff[i] = 0; loff[i] = 0; }
        }
        u32* hb = hbuf1 + (size_t)g * 4 * 16 * 400;

        for (int t = 0; t < 256; ++t) {
            float xzv[2], xrv[2], xhv[2];
            for (int e = 0; e < ne; ++e) {
                const u16* xr = xw1 + (size_t)t * 153600 + exw[e];
                xzv[e] = bf2f(xr[eih[e]]);
                xrv[e] = bf2f(xr[400 + eih[e]]);
                xhv[e] = bf2f(xr[800 + eih[e]]);
            }
            const u32* hsrc = hb + (t & 3) * 6400;
            const u32 want = (u32)t & 0xFFFFu;
            u32 pend = pend0;
            while (pend) {
                u64 tmp[13];
                #pragma unroll
                for (int i = 0; i < 13; ++i)
                    if (pend & (1u << i))
                        tmp[i] = __hip_atomic_load((const u64*)(hsrc + soff[i]),
                                                   __ATOMIC_RELAXED,
                                                   __HIP_MEMORY_SCOPE_AGENT);
                #pragma unroll
                for (int i = 0; i < 13; ++i)
                    if (pend & (1u << i)) {
                        u64 v = tmp[i];
                        if ((u32)(v & 0xFFFFu) == want &&
                            ((u32)(v >> 32) & 0xFFFFu) == want) {
                            *(u32*)(h_lds + loff[i]) =
                                ((u32)(v >> 16) & 0xFFFFu) | ((u32)(v >> 48) << 16);
                            pend &= ~(1u << i);
                        }
                    }
                if (pend) __builtin_amdgcn_s_sleep(1);
            }
            __syncthreads();

            f32x4 acc[2];
            acc[0] = (f32x4){0.f, 0.f, 0.f, 0.f};
            acc[1] = (f32x4){0.f, 0.f, 0.f, 0.f};
            for (int ks = 0; ks < 13; ++ks) {
                bf16x8 a = *(const bf16x8*)(h_lds + l15 * 424 + ks * 32 + lq * 8);
                int ti = 0;
                for (int nt = wave; nt < 5; nt += 4, ++ti) {
                    bf16x8 b = *(const bf16x8*)(U_lds + (nt * 16 + l15) * 424 + ks * 32 + lq * 8);
                    acc[ti] = __builtin_amdgcn_mfma_f32_16x16x32_bf16(a, b, acc[ti], 0, 0, 0);
                }
            }
            {
                int ti = 0;
                for (int nt = wave; nt < 5; nt += 4, ++ti)
                    for (int i = 0; i < 4; ++i)
                        rec_lds[(lq * 4 + i) * 80 + nt * 16 + l15] = acc[ti][i];
            }
            __syncthreads();

            u32* hdst = hb + ((t + 1) & 3) * 6400;
            float hnv[2]; u32 tgv[2];
            for (int e = 0; e < ne; ++e) {
                int b = eb[e], co = eco[e];
                float rz = rec_lds[b * 80 + co] + ebrz[e];
                float rr = rec_lds[b * 80 + 25 + co] + ebrr[e];
                float rh = rec_lds[b * 80 + 50 + co] + ebrh[e];
                float z = 1.f / (1.f + __expf(-(xzv[e] + rz)));
                float r = 1.f / (1.f + __expf(-(xrv[e] + rr)));
                float pre = xhv[e] + r * rh;
                float th = 2.f / (1.f + __expf(-2.f * pre)) - 1.f;
                float hn = z * hold[e] + (1.f - z) * th;
                if (!tok_lds[b * 256 + t]) hn = hold[e];
                hold[e] = hn; hnv[e] = hn;
                tgv[e] = ((u32)f2bf(hn) << 16) | (u32)(t + 1);
            }
            for (int e = 0; e < ne; ++e)
                __hip_atomic_store(hdst + eb[e] * 400 + eih[e], tgv[e],
                                   __ATOMIC_RELAXED, __HIP_MEMORY_SCOPE_AGENT);
            for (int e = 0; e < ne; ++e) {
                int gb = egb[e], ih = eih[e];
                out1[((size_t)gb * 256 + t) * 400 + ih] = hnv[e];
                o1b[(size_t)(t * 128 + gb) * 400 + ih] = (u16)(tgv[e] >> 16);
                if (t == 255) h1f[(size_t)gb * 400 + ih] = hnv[e];
            }
            // sentinel: all stores of this step drained, then count this WG
            asm volatile("s_waitcnt vmcnt(0)" ::: "memory");
            __syncthreads();
            if (tid == 0)
                __hip_atomic_fetch_add(&ctrl[16 + g], 1u, __ATOMIC_RELAXED,
                                       __HIP_MEMORY_SCOPE_AGENT);
        }
    } else {
        // ===================== GRU2 =====================
        u16* W2_lds = (u16*)smem;                      // 80*424*2 = 67840
        u16* U2_lds = (u16*)(smem + 67840);            // 80*232*2 = 37120
        u16* o1_lds = (u16*)(smem + 104960);           // 16*424*2 = 13568
        u16* h2_lds = (u16*)(smem + 118528);           // 16*232*2 = 7424
        float* xw_lds = (float*)(smem + 125952);       // 16*80*4 = 5120
        float* rc_lds = (float*)(smem + 131072);       // 16*80*4 = 5120
        unsigned char* tok_lds = (unsigned char*)(smem + 136192); // 4096

        for (int i = tid; i < 31488; i += 256) ((u32*)smem)[i] = 0u; // u16 regions
        __syncthreads();
        for (int idx = tid; idx < 15000; idx += 256) {     // W2 slice 75x400
            int c = idx / 200, kp = idx - (idx / 200) * 200;
            int j = (c / 25) * 200 + w * 25 + (c % 25);
            *(u32*)(W2_lds + c * 424 + kp * 2) =
                *(const u32*)(W2T + (size_t)j * 400 + kp * 2);
        }
        for (int idx = tid; idx < 7500; idx += 256) {      // U2 slice 75x200
            int c = idx / 100, kp = idx - (idx / 100) * 100;
            int j = (c / 25) * 200 + w * 25 + (c % 25);
            *(u32*)(U2_lds + c * 232 + kp * 2) =
                *(const u32*)(U2T + (size_t)j * 200 + kp * 2);
        }
        for (int i = tid; i < 4096; i += 256) {
            int b = i >> 8, tt = i & 255;
            tok_lds[i] = (tokens[(b0 + b) * 256 + tt] != 0) ? 1 : 0;
        }

        int ne = 0;
        int eb[2], eco[2], eih[2], egb[2];
        float ebiz[2], ebir[2], ebih[2], ebrz[2], ebrr[2], ebrh[2], hold[2];
        for (int u = tid; u < 400; u += 256) {
            int b = u / 25, co = u % 25;
            int ih = w * 25 + co;
            eb[ne] = b; eco[ne] = co; eih[ne] = ih; egb[ne] = b0 + b;
            ebiz[ne] = b2[ih];       ebir[ne] = b2[200 + ih];  ebih[ne] = b2[400 + ih];
            ebrz[ne] = b2[600 + ih]; ebrr[ne] = b2[800 + ih];  ebrh[ne] = b2[1000 + ih];
            hold[ne] = 0.f; ++ne;
        }
        u32 pend0 = 0; int soff[7], loff[7];
        for (int i = 0; i < 7; ++i) {
            int s = tid + i * 256;
            if (s < 1600) {
                int b = s / 100, kk = s % 100;
                soff[i] = b * 200 + kk * 2; loff[i] = b * 232 + kk * 2;
                pend0 |= 1u << i;
            } else { soff[i] = 0; loff[i] = 0; }
        }
        u32* hb = hbuf2 + (size_t)g * 4 * 16 * 200;
        __syncthreads();

        for (int t = 0; t < 256; ++t) {
            // 1. wait for GRU1 group g to finish step t (monotonic counter)
            const u32 need = 16u * (u32)(t + 1);
            while (__hip_atomic_load(&ctrl[16 + g], __ATOMIC_RELAXED,
                                     __HIP_MEMORY_SCOPE_AGENT) < need)
                __builtin_amdgcn_s_sleep(2);
            asm volatile("" ::: "memory");

            // 2. stage out1[t] tile (16 x 400 bf16, contiguous rows)
            const u32* src = (const u32*)(o1b + (size_t)(t * 128 + b0) * 400);
            for (int idx = tid; idx < 3200; idx += 256) {
                int row = idx / 200, k = idx - row * 200;
                *(u32*)(o1_lds + row * 424 + k * 2) = src[idx];
            }

            // 3. own h2 tagged poll
            const u32* hsrc = hb + (t & 3) * 3200;
            const u32 want = (u32)t & 0xFFFFu;
            u32 pend = pend0;
            while (pend) {
                u64 tmp[7];
                #pragma unroll
                for (int i = 0; i < 7; ++i)
                    if (pend & (1u << i))
                        tmp[i] = __hip_atomic_load((const u64*)(hsrc + soff[i]),
                                                   __ATOMIC_RELAXED,
                                                   __HIP_MEMORY_SCOPE_AGENT);
                #pragma unroll
                for (int i = 0; i < 7; ++i)
                    if (pend & (1u << i)) {
                        u64 v = tmp[i];
                        if ((u32)(v & 0xFFFFu) == want &&
                            ((u32)(v >> 32) & 0xFFFFu) == want) {
                            *(u32*)(h2_lds + loff[i]) =
                                ((u32)(v >> 16) & 0xFFFFu) | ((u32)(v >> 48) << 16);
                            pend &= ~(1u << i);
                        }
                    }
                if (pend) __builtin_amdgcn_s_sleep(1);
            }
            __syncthreads();

            // 4. MFMA: xw-part (o1b @ W2slice, K=400) and rec-part (h2 @ U2slice, K=200)
            f32x4 aw[2], au[2];
            aw[0] = (f32x4){0.f,0.f,0.f,0.f}; aw[1] = (f32x4){0.f,0.f,0.f,0.f};
            au[0] = (f32x4){0.f,0.f,0.f,0.f}; au[1] = (f32x4){0.f,0.f,0.f,0.f};
            for (int ks = 0; ks < 13; ++ks) {
                bf16x8 a = *(const bf16x8*)(o1_lds + l15 * 424 + ks * 32 + lq * 8);
                int ti = 0;
                for (int nt = wave; nt < 5; nt += 4, ++ti) {
                    bf16x8 b = *(const bf16x8*)(W2_lds + (nt * 16 + l15) * 424 + ks * 32 + lq * 8);
                    aw[ti] = __builtin_amdgcn_mfma_f32_16x16x32_bf16(a, b, aw[ti], 0, 0, 0);
                }
            }
            for (int ks = 0; ks < 7; ++ks) {
                bf16x8 a = *(const bf16x8*)(h2_lds + l15 * 232 + ks * 32 + lq * 8);
                int ti = 0;
                for (int nt = wave; nt < 5; nt += 4, ++ti) {
                    bf16x8 b = *(const bf16x8*)(U2_lds + (nt * 16 + l15) * 232 + ks * 32 + lq * 8);
                    au[ti] = __builtin_amdgcn_mfma_f32_16x16x32_bf16(a, b, au[ti], 0, 0, 0);
                }
            }
            {
                int ti = 0;
                for (int nt = wave; nt < 5; nt += 4, ++ti)
                    for (int i = 0; i < 4; ++i) {
                        xw_lds[(lq * 4 + i) * 80 + nt * 16 + l15] = aw[ti][i];
                        rc_lds[(lq * 4 + i) * 80 + nt * 16 + l15] = au[ti][i];
                    }
            }
            __syncthreads();

            // 5. gates (xw and rec kept separate for reset_after h-gate)
            u32* hdst = hb + ((t + 1) & 3) * 3200;
            float hnv[2]; u32 tgv[2];
            for (int e = 0; e < ne; ++e) {
                int b = eb[e], co = eco[e];
                float xz = xw_lds[b * 80 + co] + ebiz[e];
                float rz = rc_lds[b * 80 + co] + ebrz[e];
                float xr = xw_lds[b * 80 + 25 + co] + ebir[e];
                float rr = rc_lds[b * 80 + 25 + co] + ebrr[e];
                float xh = xw_lds[b * 80 + 50 + co] + ebih[e];
                float rh = rc_lds[b * 80 + 50 + co] + ebrh[e];
                float z = 1.f / (1.f + __expf(-(xz + rz)));
                float r = 1.f / (1.f + __expf(-(xr + rr)));
                float pre = xh + r * rh;
                float th = 2.f / (1.f + __expf(-2.f * pre)) - 1.f;
                float hn = z * hold[e] + (1.f - z) * th;
                if (!tok_lds[b * 256 + t]) hn = hold[e];
                hold[e] = hn; hnv[e] = hn;
                tgv[e] = ((u32)f2bf(hn) << 16) | (u32)(t + 1);
            }
            for (int e = 0; e < ne; ++e)
                __hip_atomic_store(hdst + eb[e] * 200 + eih[e], tgv[e],
                                   __ATOMIC_RELAXED, __HIP_MEMORY_SCOPE_AGENT);
            for (int e = 0; e < ne; ++e) {
                int gb = egb[e], ih = eih[e];
                out2[((size_t)gb * 256 + t) * 200 + ih] = hnv[e];
                if (t == 255) h2f[(size_t)gb * 200 + ih] = hnv[e];
            }
        }
    }
}

// ---------------------------------------------------------------------------
// launch
// ---------------------------------------------------------------------------
extern "C" void kernel_launch(void* const* d_in, const int* in_sizes, int n_in,
                              void* d_out, int out_size, void* d_ws, size_t ws_size,
                              hipStream_t stream)
{
    const int*   tokens = (const int*)d_in[0];
    const float* emb    = (const float*)d_in[1];
    const float* gamma  = (const float*)d_in[2];
    const float* beta   = (const float*)d_in[3];
    const float* mmean  = (const float*)d_in[4];
    const float* mvar   = (const float*)d_in[5];
    const float* W1     = (const float*)d_in[6];
    const float* U1     = (const float*)d_in[7];
    const float* b1     = (const float*)d_in[8];
    const float* W2     = (const float*)d_in[9];
    const float* U2     = (const float*)d_in[10];
    const float* b2     = (const float*)d_in[11];

    float* out = (float*)d_out;
    char* ws = (char*)d_ws;

    u16* x     = (u16*)(ws + 0);            // 32768*200*2  = 13,107,200
    u16* xw1   = (u16*)(ws + 13107200);     // 32768*1200*2 = 78,643,200
    u16* o1b   = (u16*)(ws + 91750400);     // 32768*400*2  = 26,214,400
    // (xw2 region unused now)
    u16* W1T   = (u16*)(ws + 157286400);    // 480,000
    u16* W2T   = (u16*)(ws + 157766400);    // 480,000
    u16* U1T   = (u16*)(ws + 158246400);    // 960,000
    u16* U2T   = (u16*)(ws + 159206400);    // 240,000
    u32* hbuf1 = (u32*)(ws + 159446400);    // 8*4*16*400 u32 = 819,200 B
    u32* hbuf2 = (u32*)(ws + 160265600);    // 8*4*16*200 u32 = 409,600 B
    u32* ctrl  = (u32*)(ws + 160675200);    // 24 u32: clmA, clmB, sent

    float* out2 = out;              // [128,256,200]
    float* out1 = out + 6553600;    // [128,256,400]
    float* h2   = out + 19660800;   // [128,200]
    float* h1   = out + 19686400;   // [128,400]

    prep_kernel<<<5420, 256, 0, stream>>>(W1, W2, U1, U2, W1T, W2T, U1T, U2T,
                                          hbuf1);
    embed_bn_kernel<<<25600, 256, 0, stream>>>(tokens, emb, gamma, beta, mmean,
                                               mvar, x);
    // xw1 = x @ W1 + bi1   ([32768,200]@[200,1200])
    gemm_bias_kernel<200, 7, 232><<<dim3(512, 19), 256, 0, stream>>>(
        x, W1T, b1, xw1, 1200);
    // fused GRU1 (128 WGs) + GRU2 (64 WGs) pipeline
    fused_gru_kernel<<<192, 256, 0, stream>>>(
        xw1, U1T, b1 + 1200, W2T, U2T, b2, tokens,
        out1, o1b, h1, out2, h2, hbuf1, hbuf2, ctrl);
}